// Round 19
// baseline (289.068 us; speedup 1.0000x reference)
//
#include <hip/hip_runtime.h>
#include <hip/hip_bf16.h>
#include <math.h>

#define N_PTS 8192
#define D_FEAT 64
#define TPB 256                // 4 waves
#define ROWS_B 32              // i-rows per block
#define JSPLIT 4               // j-range split across blocks
#define JRANGE (N_PTS / JSPLIT)      // 2048
#define CHUNKS_PB (JRANGE / 32)      // 64 chunks per block
#define PASSES (CHUNKS_PB / 4)       // 16 (4 waves)
#define LSTRIDE 132            // merge LDS row stride (floats)

typedef __attribute__((ext_vector_type(8))) short short8v;   // 8 bf16 = 4 VGPR
typedef __attribute__((ext_vector_type(16))) float f32x16;   // 32x32 MFMA acc

// Fragment-major hi-only layout: unit u (16B = 8 bf16 of K=64) of row r in
// chunk c lives at short-offset ((c*8 + u)*32 + (r&31)) * 8.
__device__ ushort g_X2[N_PTS * D_FEAT];   // 1 MB packed bf16
__device__ float  g_x2n[N_PTS];           // exact f32 squared norms
__device__ float  g_part[N_PTS * 64];     // 2 MB: per-row 4x sorted-16 keys
__device__ float  g_md[N_PTS];            // mean NN distance
__device__ int    g_cnt[N_PTS / ROWS_B];  // per-i-chunk arrival counters

// ---- pack: 2 threads/row -> bf16 (RNE), fragment-major + exact f32 norm ----
__global__ __launch_bounds__(256) void pack_kernel(const float* __restrict__ x) {
    // zero the finisher counters each launch (pack runs before nn in-stream)
    if (blockIdx.x == 0 && threadIdx.x < N_PTS / ROWS_B)
        g_cnt[threadIdx.x] = 0;
    const int gt = blockIdx.x * 256 + threadIdx.x;
    const int row = gt >> 1, half = gt & 1;
    const int chunk = row >> 5, r = row & 31;
    const float4* xr = (const float4*)(x + (size_t)row * D_FEAT + half * 32);
    ushort* base = g_X2 + (size_t)chunk * 2048 + r * 8;
    float norm = 0.f;
    #pragma unroll
    for (int it = 0; it < 4; ++it) {      // 8 dims -> unit half*4+it
        float4 a = xr[2 * it], b = xr[2 * it + 1];
        float vals[8] = {a.x, a.y, a.z, a.w, b.x, b.y, b.z, b.w};
        uint hi[8];
        #pragma unroll
        for (int e = 0; e < 8; ++e) {
            float v = vals[e];
            norm += v * v;
            uint u = __float_as_uint(v);
            hi[e] = (u + 0x7fffu + ((u >> 16) & 1u)) >> 16;   // RNE bf16
        }
        *(uint4*)(base + (half * 4 + it) * 256) = make_uint4(
            hi[0] | (hi[1] << 16), hi[2] | (hi[3] << 16),
            hi[4] | (hi[5] << 16), hi[6] | (hi[7] << 16));
    }
    norm += __shfl_xor(norm, 1);          // combine the two halves
    if (half == 0) g_x2n[row] = norm;
}

// ascending compare-exchange via raw ISA min/max: exactly 2 VALU inst.
#define CE(A, B) { float lo_, hi_; \
    asm("v_min_f32 %0, %2, %3\n\tv_max_f32 %1, %2, %3" \
        : "=&v"(lo_), "=&v"(hi_) : "v"(A), "v"(B)); \
    A = lo_; B = hi_; }
#define VMIN(D, A, B) { float r_; \
    asm("v_min_f32 %0, %1, %2" : "=v"(r_) : "v"(A), "v"(B)); D = r_; }

// ---- main: K=64 Gram-MFMA + Batcher top-16 + LDS merge + finisher ----
__global__ __launch_bounds__(TPB, 4) void nn_kernel() {
    __shared__ float s_mem[32 * LSTRIDE];  // 16.9 KB: slice norms, then lists
    const int t    = threadIdx.x;
    const int lane = t & 63;
    const int w    = t >> 6;       // wave 0..3
    const int il   = lane & 31;    // row-in-chunk
    const int h    = lane >> 5;    // unit parity
    const int ib   = blockIdx.x >> 2;        // i-chunk 0..255
    const int js   = blockIdx.x & 3;         // j-slice 0..3
    const int i0   = ib * ROWS_B;
    const int c0   = js * CHUNKS_PB;         // first global j-chunk
    const float INF = __builtin_inff();

    // stage this slice's norms into LDS (2048 floats, 2 float4/thread)
    {
        float4* s4 = (float4*)s_mem;
        const float4* g4 = (const float4*)(g_x2n + js * JRANGE);
        #pragma unroll
        for (int q = 0; q < 2; ++q) s4[t + q * TPB] = g4[t + q * TPB];
    }

    const short8v* Xf = (const short8v*)g_X2;   // 16B-unit granular

    // B-frag: block's 32 i-rows, K=64, persistent (16 regs)
    short8v bfr[4];
    {
        const short8v* bp = Xf + ((size_t)ib * 8 + h) * 32 + il;
        #pragma unroll
        for (int tt = 0; tt < 4; ++tt) bfr[tt] = bp[tt * 64];
    }
    __syncthreads();

    float t16[16];
    #pragma unroll
    for (int k = 0; k < 16; ++k) t16[k] = INF;

    // wave's chunk for pass p: c0 + p*4 + w (pass stride = 4 chunks = 1024)
    const short8v* abase = Xf + ((size_t)(c0 + w) * 8 + h) * 32 + il;
    #define ALOAD(dst, p) { \
        const short8v* ab_ = abase + (size_t)(p) * 1024; \
        _Pragma("unroll") \
        for (int tt = 0; tt < 4; ++tt) dst[tt] = ab_[tt * 64]; }

    #define EPILOG(accv, p) { \
        const int cl_ = (p) * 4 + w; \
        float c[16]; \
        _Pragma("unroll") \
        for (int g = 0; g < 4; ++g) { \
            float4 xq = *(const float4*)&s_mem[cl_ * 32 + 8 * g + 4 * h]; \
            float cand[4] = {xq.x, xq.y, xq.z, xq.w}; \
            _Pragma("unroll") \
            for (int e = 0; e < 4; ++e) \
                c[4 * g + e] = fmaf(-2.f, accv[4 * g + e], cand[e]); \
        } \
        /* Batcher merge-exchange sort-16, ascending (63 CE) */ \
        CE(c[0],c[8]) CE(c[1],c[9]) CE(c[2],c[10]) CE(c[3],c[11]) \
        CE(c[4],c[12]) CE(c[5],c[13]) CE(c[6],c[14]) CE(c[7],c[15]) \
        CE(c[0],c[4]) CE(c[1],c[5]) CE(c[2],c[6]) CE(c[3],c[7]) \
        CE(c[8],c[12]) CE(c[9],c[13]) CE(c[10],c[14]) CE(c[11],c[15]) \
        CE(c[4],c[8]) CE(c[5],c[9]) CE(c[6],c[10]) CE(c[7],c[11]) \
        CE(c[0],c[2]) CE(c[1],c[3]) CE(c[4],c[6]) CE(c[5],c[7]) \
        CE(c[8],c[10]) CE(c[9],c[11]) CE(c[12],c[14]) CE(c[13],c[15]) \
        CE(c[2],c[8]) CE(c[3],c[9]) CE(c[6],c[12]) CE(c[7],c[13]) \
        CE(c[2],c[4]) CE(c[3],c[5]) CE(c[6],c[8]) CE(c[7],c[9]) \
        CE(c[10],c[12]) CE(c[11],c[13]) \
        CE(c[0],c[1]) CE(c[2],c[3]) CE(c[4],c[5]) CE(c[6],c[7]) \
        CE(c[8],c[9]) CE(c[10],c[11]) CE(c[12],c[13]) CE(c[14],c[15]) \
        CE(c[1],c[8]) CE(c[3],c[10]) CE(c[5],c[12]) CE(c[7],c[14]) \
        CE(c[1],c[4]) CE(c[3],c[6]) CE(c[5],c[8]) CE(c[7],c[10]) \
        CE(c[9],c[12]) CE(c[11],c[14]) \
        CE(c[1],c[2]) CE(c[3],c[4]) CE(c[5],c[6]) CE(c[7],c[8]) \
        CE(c[9],c[10]) CE(c[11],c[12]) CE(c[13],c[14]) \
        /* merge-keep-16: pairwise min vs reversed batch -> bitonic cleanup */ \
        _Pragma("unroll") \
        for (int i = 0; i < 16; ++i) VMIN(t16[i], t16[i], c[15 - i]) \
        _Pragma("unroll") \
        for (int j = 8; j > 0; j >>= 1) { \
            _Pragma("unroll") \
            for (int i = 0; i < 16; ++i) { \
                const int ix = i ^ j; \
                if (ix > i) { CE(t16[i], t16[ix]) } \
            } \
        } }

    #define MFMA4(accv, areg) { \
        _Pragma("unroll") \
        for (int r = 0; r < 16; ++r) accv[r] = 0.f; \
        _Pragma("unroll") \
        for (int tt = 0; tt < 4; ++tt) \
            accv = __builtin_amdgcn_mfma_f32_32x32x16_bf16(areg[tt], bfr[tt], accv, 0, 0, 0); }

    short8v a0[4], a1[4];
    f32x16 acc;
    ALOAD(a0, 0);
    #pragma unroll 1
    for (int pp = 0; pp < PASSES / 2; ++pp) {
        const int p0 = 2 * pp, p1 = 2 * pp + 1;
        ALOAD(a1, p1);                         // prefetch p1
        MFMA4(acc, a0);
        EPILOG(acc, p0);                       // hides prefetch + mfma latency
        if (pp < PASSES / 2 - 1) ALOAD(a0, p0 + 2);
        MFMA4(acc, a1);
        EPILOG(acc, p1);
    }

    // drop the self-pair: strict minimum (key ~ -x2i) of exactly one lane,
    // only in the slice/wave that owns chunk ib.
    {
        const bool own = ((ib >> 6) == js) && (w == (ib & 3)) &&
                         (h == ((il >> 2) & 1));
        if (own) {
            #pragma unroll
            for (int k = 0; k < 15; ++k) t16[k] = t16[k + 1];
            t16[15] = INF;
        }
    }

    __syncthreads();   // norm reads done; overlay lists into s_mem
    {
        const int list = w * 2 + h;            // 0..7
        float* dst = &s_mem[il * LSTRIDE + list * 16];
        *(float4*)(dst + 0)  = make_float4(t16[0],  t16[1],  t16[2],  t16[3]);
        *(float4*)(dst + 4)  = make_float4(t16[4],  t16[5],  t16[6],  t16[7]);
        *(float4*)(dst + 8)  = make_float4(t16[8],  t16[9],  t16[10], t16[11]);
        *(float4*)(dst + 12) = make_float4(t16[12], t16[13], t16[14], t16[15]);
    }
    __syncthreads();

    // per-slice merge: 8 sorted lists/row -> sorted top-16 keys to g_part.
    // 8-lane groups, 8 rows per wave.
    {
        const int q  = lane >> 3;              // row-sub 0..7
        const int sl = lane & 7;               // list id 0..7
        const int r  = w * 8 + q;
        const int row = i0 + r;
        float tl[16];
        {
            const float* src = &s_mem[r * LSTRIDE + sl * 16];
            float4 q0 = *(const float4*)(src + 0);
            float4 q1 = *(const float4*)(src + 4);
            float4 q2 = *(const float4*)(src + 8);
            float4 q3 = *(const float4*)(src + 12);
            tl[0]=q0.x; tl[1]=q0.y; tl[2]=q0.z; tl[3]=q0.w;
            tl[4]=q1.x; tl[5]=q1.y; tl[6]=q1.z; tl[7]=q1.w;
            tl[8]=q2.x; tl[9]=q2.y; tl[10]=q2.z; tl[11]=q2.w;
            tl[12]=q3.x; tl[13]=q3.y; tl[14]=q3.z; tl[15]=q3.w;
        }
        #pragma unroll 1
        for (int it = 0; it < 16; ++it) {
            float m = tl[0]; int src = sl;
            #pragma unroll
            for (int off = 4; off > 0; off >>= 1) {   // within 8-lane group
                float om = __shfl_xor(m, off);
                int os = __shfl_xor(src, off);
                if (om < m || (om == m && os < src)) { m = om; src = os; }
            }
            if (sl == 0) g_part[row * 64 + js * 16 + it] = m;
            const bool pop = (sl == src);
            #pragma unroll
            for (int k = 0; k < 15; ++k) tl[k] = pop ? tl[k + 1] : tl[k];
            tl[15] = pop ? INF : tl[15];
        }
    }

    // ---- last-arrival finisher: merge 4x16 keys per row -> g_md ----
    __threadfence();                       // release g_part writes
    __shared__ int s_go;
    if (t == 0) {
        int old = atomicAdd(&g_cnt[ib], 1);
        s_go = (old == JSPLIT - 1) ? 1 : 0;
    }
    __syncthreads();
    if (s_go) {
        __threadfence();                   // acquire other slices' writes
        #pragma unroll 1
        for (int q = 0; q < 8; ++q) {
            const int row = i0 + w * 8 + q;
            float v = g_part[row * 64 + lane];   // 64 keys, 1/lane
            const float x2r = g_x2n[row];
            float sum = 0.f;
            #pragma unroll 1
            for (int it = 0; it < 16; ++it) {
                float m = v; int src = lane;
                #pragma unroll
                for (int off = 32; off > 0; off >>= 1) {
                    float om = __shfl_xor(m, off);
                    int os = __shfl_xor(src, off);
                    if (om < m || (om == m && os < src)) { m = om; src = os; }
                }
                sum += sqrtf(fmaxf(m + x2r, 0.f));
                if (lane == src) v = INF;
            }
            if (lane == 0) g_md[row] = sum * (1.f / 16.f);
        }
    }
}

// ---- scalar loss ----
__global__ __launch_bounds__(1024) void loss_kernel(float* __restrict__ out) {
    __shared__ float s[1024];
    const int t = threadIdx.x;

    float m = -__builtin_inff();
    for (int j = t; j < N_PTS; j += 1024) m = fmaxf(m, g_md[j]);
    s[t] = m; __syncthreads();
    for (int off = 512; off > 0; off >>= 1) {
        if (t < off) s[t] = fmaxf(s[t], s[t + off]);
        __syncthreads();
    }
    m = s[0]; __syncthreads();

    float se = 0.f, sm = 0.f;
    for (int j = t; j < N_PTS; j += 1024) {
        float v = g_md[j];
        se += expf(v - m);
        sm += v;
    }
    s[t] = se; __syncthreads();
    for (int off = 512; off > 0; off >>= 1) {
        if (t < off) s[t] += s[t + off];
        __syncthreads();
    }
    float S = s[0]; __syncthreads();
    s[t] = sm; __syncthreads();
    for (int off = 512; off > 0; off >>= 1) {
        if (t < off) s[t] += s[t + off];
        __syncthreads();
    }
    float M = s[0];

    if (t == 0) {
        const float n = (float)N_PTS;
        out[0] = -logf(n) - M / n + (m + logf(S));
    }
}

extern "C" void kernel_launch(void* const* d_in, const int* in_sizes, int n_in,
                              void* d_out, int out_size, void* d_ws, size_t ws_size,
                              hipStream_t stream) {
    const float* x = (const float*)d_in[0];
    float* out = (float*)d_out;

    pack_kernel<<<N_PTS * 2 / 256, 256, 0, stream>>>(x);
    nn_kernel<<<(N_PTS / ROWS_B) * JSPLIT, TPB, 0, stream>>>();
    loss_kernel<<<1, 1024, 0, stream>>>(out);
}

// Round 20
// 56.002 us; speedup vs baseline: 5.1617x; 5.1617x over previous
//
#include <hip/hip_runtime.h>
#include <hip/hip_bf16.h>
#include <math.h>

#define N_PTS 8192
#define D_FEAT 64
#define TPB 1024               // 16 waves
#define ROWS_B 32              // i-rows per block
#define PASSES 16              // 256 chunks / 16 waves
#define RSTR 648               // merge LDS row stride (floats)
#define LSTR 20                // merge LDS list stride (floats, 16B-aligned)

typedef __attribute__((ext_vector_type(8))) short short8v;   // 8 bf16 = 4 VGPR
typedef __attribute__((ext_vector_type(16))) float f32x16;   // 32x32 MFMA acc

// Fragment-major hi-only layout: unit u (16B = 8 bf16 of K=64) of row r in
// chunk c lives at short-offset ((c*8 + u)*32 + (r&31)) * 8.
__device__ ushort g_X2[N_PTS * D_FEAT];   // 1 MB packed bf16 (hi only)
__device__ float  g_x2n[N_PTS];           // exact f32 squared norms
__device__ float  g_md[N_PTS];            // mean NN distance

// ---- pack: fp32 row -> bf16 (RNE), fragment-major + exact f32 norm ----
__global__ __launch_bounds__(256) void pack_kernel(const float* __restrict__ x) {
    const int row = blockIdx.x * 256 + threadIdx.x;
    const int chunk = row >> 5, r = row & 31;
    const float4* xr = (const float4*)(x + (size_t)row * D_FEAT);
    ushort* base = g_X2 + (size_t)chunk * 2048 + r * 8;   // unit stride = 256 shorts
    float norm = 0.f;
    #pragma unroll
    for (int it = 0; it < 8; ++it) {      // dims 8it..8it+7 -> unit it
        float4 a = xr[2 * it], b = xr[2 * it + 1];
        float vals[8] = {a.x, a.y, a.z, a.w, b.x, b.y, b.z, b.w};
        uint hi[8];
        #pragma unroll
        for (int e = 0; e < 8; ++e) {
            float v = vals[e];
            norm += v * v;
            uint u = __float_as_uint(v);
            hi[e] = (u + 0x7fffu + ((u >> 16) & 1u)) >> 16;   // RNE bf16
        }
        *(uint4*)(base + it * 256) = make_uint4(
            hi[0] | (hi[1] << 16), hi[2] | (hi[3] << 16),
            hi[4] | (hi[5] << 16), hi[6] | (hi[7] << 16));
    }
    g_x2n[row] = norm;
}

// compare-exchange: ascending
#define CE(A, B) { float lo_ = fminf(A, B); float hi_ = fmaxf(A, B); A = lo_; B = hi_; }

// ---- main: K=64 Gram-MFMA + Batcher top-16 + in-LDS merge ----
__global__ __launch_bounds__(TPB, 4) void nn_kernel() {
    __shared__ float s_mem[32 * RSTR];   // 83KB: norms[8192] then lists overlay
    const int t    = threadIdx.x;
    const int lane = t & 63;
    const int w    = t >> 6;       // wave 0..15
    const int il   = lane & 31;    // row-in-chunk
    const int h    = lane >> 5;    // unit parity / j-subgroup
    const int ib   = blockIdx.x;   // i-chunk 0..255
    const int i0   = ib * ROWS_B;
    const float INF = __builtin_inff();

    // stage ALL norms into LDS (8192 floats, 2 float4/thread)
    {
        float4* s4 = (float4*)s_mem;
        const float4* g4 = (const float4*)g_x2n;
        #pragma unroll
        for (int q = 0; q < 2; ++q) s4[t + q * TPB] = g4[t + q * TPB];
    }

    const short8v* Xf = (const short8v*)g_X2;   // 16B-unit granular

    // B-frag: block's 32 i-rows, K=64, persistent (16 regs)
    short8v bfr[4];
    {
        const short8v* bp = Xf + ((size_t)ib * 8 + h) * 32 + il;
        #pragma unroll
        for (int tt = 0; tt < 4; ++tt) bfr[tt] = bp[tt * 64];
    }
    __syncthreads();

    float t16[16];
    #pragma unroll
    for (int k = 0; k < 16; ++k) t16[k] = INF;

    // wave's chunk for pass p: p*16 + w
    const short8v* abase = Xf + ((size_t)w * 8 + h) * 32 + il;
    #define ALOAD(dst, p) { \
        const short8v* ab_ = abase + (size_t)(p) * 4096; \
        _Pragma("unroll") \
        for (int tt = 0; tt < 4; ++tt) dst[tt] = ab_[tt * 64]; }

    #define EPILOG(accv, p) { \
        const int cl_ = (p) * 16 + w; \
        float c[16]; \
        _Pragma("unroll") \
        for (int g = 0; g < 4; ++g) { \
            float4 xq = *(const float4*)&s_mem[cl_ * 32 + 8 * g + 4 * h]; \
            float cand[4] = {xq.x, xq.y, xq.z, xq.w}; \
            _Pragma("unroll") \
            for (int e = 0; e < 4; ++e) \
                c[4 * g + e] = fmaf(-2.f, accv[4 * g + e], cand[e]); \
        } \
        /* Batcher merge-exchange sort-16, ascending (63 CE) */ \
        CE(c[0],c[8]) CE(c[1],c[9]) CE(c[2],c[10]) CE(c[3],c[11]) \
        CE(c[4],c[12]) CE(c[5],c[13]) CE(c[6],c[14]) CE(c[7],c[15]) \
        CE(c[0],c[4]) CE(c[1],c[5]) CE(c[2],c[6]) CE(c[3],c[7]) \
        CE(c[8],c[12]) CE(c[9],c[13]) CE(c[10],c[14]) CE(c[11],c[15]) \
        CE(c[4],c[8]) CE(c[5],c[9]) CE(c[6],c[10]) CE(c[7],c[11]) \
        CE(c[0],c[2]) CE(c[1],c[3]) CE(c[4],c[6]) CE(c[5],c[7]) \
        CE(c[8],c[10]) CE(c[9],c[11]) CE(c[12],c[14]) CE(c[13],c[15]) \
        CE(c[2],c[8]) CE(c[3],c[9]) CE(c[6],c[12]) CE(c[7],c[13]) \
        CE(c[2],c[4]) CE(c[3],c[5]) CE(c[6],c[8]) CE(c[7],c[9]) \
        CE(c[10],c[12]) CE(c[11],c[13]) \
        CE(c[0],c[1]) CE(c[2],c[3]) CE(c[4],c[5]) CE(c[6],c[7]) \
        CE(c[8],c[9]) CE(c[10],c[11]) CE(c[12],c[13]) CE(c[14],c[15]) \
        CE(c[1],c[8]) CE(c[3],c[10]) CE(c[5],c[12]) CE(c[7],c[14]) \
        CE(c[1],c[4]) CE(c[3],c[6]) CE(c[5],c[8]) CE(c[7],c[10]) \
        CE(c[9],c[12]) CE(c[11],c[14]) \
        CE(c[1],c[2]) CE(c[3],c[4]) CE(c[5],c[6]) CE(c[7],c[8]) \
        CE(c[9],c[10]) CE(c[11],c[12]) CE(c[13],c[14]) \
        /* merge-keep-16: pairwise min vs reversed batch -> bitonic cleanup */ \
        _Pragma("unroll") \
        for (int i = 0; i < 16; ++i) t16[i] = fminf(t16[i], c[15 - i]); \
        _Pragma("unroll") \
        for (int j = 8; j > 0; j >>= 1) { \
            _Pragma("unroll") \
            for (int i = 0; i < 16; ++i) { \
                const int ix = i ^ j; \
                if (ix > i) { \
                    float lo = fminf(t16[i], t16[ix]); \
                    float hi = fmaxf(t16[i], t16[ix]); \
                    t16[i] = lo; \
                    t16[ix] = hi; \
                } \
            } \
        } }

    #define MFMA4(accv, areg) { \
        _Pragma("unroll") \
        for (int r = 0; r < 16; ++r) accv[r] = 0.f; \
        _Pragma("unroll") \
        for (int tt = 0; tt < 4; ++tt) \
            accv = __builtin_amdgcn_mfma_f32_32x32x16_bf16(areg[tt], bfr[tt], accv, 0, 0, 0); }

    short8v a0[4], a1[4];
    f32x16 acc;
    ALOAD(a0, 0);
    #pragma unroll 1
    for (int pp = 0; pp < PASSES / 2; ++pp) {
        const int p0 = 2 * pp, p1 = 2 * pp + 1;
        ALOAD(a1, p1);                         // prefetch p1
        MFMA4(acc, a0);
        EPILOG(acc, p0);                       // hides prefetch + mfma latency
        if (pp < PASSES / 2 - 1) ALOAD(a0, p0 + 2);
        MFMA4(acc, a1);
        EPILOG(acc, p1);
    }

    // drop the self-pair: strict minimum (key ~ -x2i) of exactly one lane
    {
        const bool own = (w == (ib & 15)) && (h == ((il >> 2) & 1));
        if (own) {
            #pragma unroll
            for (int k = 0; k < 15; ++k) t16[k] = t16[k + 1];
            t16[15] = INF;
        }
    }

    __syncthreads();   // all norm reads done; overlay lists into s_mem
    {
        const int list = w * 2 + h;            // 0..31
        float* dst = &s_mem[il * RSTR + list * LSTR];
        *(float4*)(dst + 0)  = make_float4(t16[0],  t16[1],  t16[2],  t16[3]);
        *(float4*)(dst + 4)  = make_float4(t16[4],  t16[5],  t16[6],  t16[7]);
        *(float4*)(dst + 8)  = make_float4(t16[8],  t16[9],  t16[10], t16[11]);
        *(float4*)(dst + 12) = make_float4(t16[12], t16[13], t16[14], t16[15]);
    }
    __syncthreads();

    // merge: 32 sorted lists per row; 32-lane groups, 2 rows per wave
    {
        const int q  = lane >> 5;              // row-sub 0/1
        const int sl = lane & 31;              // list id
        const int r  = w * 2 + q;
        const int row = i0 + r;
        float tl[16];
        {
            const float* src = &s_mem[r * RSTR + sl * LSTR];
            float4 q0 = *(const float4*)(src + 0);
            float4 q1 = *(const float4*)(src + 4);
            float4 q2 = *(const float4*)(src + 8);
            float4 q3 = *(const float4*)(src + 12);
            tl[0]=q0.x; tl[1]=q0.y; tl[2]=q0.z; tl[3]=q0.w;
            tl[4]=q1.x; tl[5]=q1.y; tl[6]=q1.z; tl[7]=q1.w;
            tl[8]=q2.x; tl[9]=q2.y; tl[10]=q2.z; tl[11]=q2.w;
            tl[12]=q3.x; tl[13]=q3.y; tl[14]=q3.z; tl[15]=q3.w;
        }
        const float x2r = g_x2n[row];
        float sum = 0.f;
        #pragma unroll 1
        for (int it = 0; it < 16; ++it) {
            float m = tl[0]; int src = sl;
            #pragma unroll
            for (int off = 16; off > 0; off >>= 1) {   // within 32-lane group
                float om = __shfl_xor(m, off);
                int os = __shfl_xor(src, off);
                if (om < m || (om == m && os < src)) { m = om; src = os; }
            }
            sum += sqrtf(fmaxf(m + x2r, 0.f));
            const bool pop = (sl == src);
            #pragma unroll
            for (int k = 0; k < 15; ++k) tl[k] = pop ? tl[k + 1] : tl[k];
            tl[15] = pop ? INF : tl[15];
        }
        if (sl == 0) g_md[row] = sum * (1.f / 16.f);
    }
}

// ---- scalar loss ----
__global__ __launch_bounds__(1024) void loss_kernel(float* __restrict__ out) {
    __shared__ float s[1024];
    const int t = threadIdx.x;

    float m = -__builtin_inff();
    for (int j = t; j < N_PTS; j += 1024) m = fmaxf(m, g_md[j]);
    s[t] = m; __syncthreads();
    for (int off = 512; off > 0; off >>= 1) {
        if (t < off) s[t] = fmaxf(s[t], s[t + off]);
        __syncthreads();
    }
    m = s[0]; __syncthreads();

    float se = 0.f, sm = 0.f;
    for (int j = t; j < N_PTS; j += 1024) {
        float v = g_md[j];
        se += expf(v - m);
        sm += v;
    }
    s[t] = se; __syncthreads();
    for (int off = 512; off > 0; off >>= 1) {
        if (t < off) s[t] += s[t + off];
        __syncthreads();
    }
    float S = s[0]; __syncthreads();
    s[t] = sm; __syncthreads();
    for (int off = 512; off > 0; off >>= 1) {
        if (t < off) s[t] += s[t + off];
        __syncthreads();
    }
    float M = s[0];

    if (t == 0) {
        const float n = (float)N_PTS;
        out[0] = -logf(n) - M / n + (m + logf(S));
    }
}

extern "C" void kernel_launch(void* const* d_in, const int* in_sizes, int n_in,
                              void* d_out, int out_size, void* d_ws, size_t ws_size,
                              hipStream_t stream) {
    const float* x = (const float*)d_in[0];
    float* out = (float*)d_out;

    pack_kernel<<<N_PTS / 256, 256, 0, stream>>>(x);
    nn_kernel<<<N_PTS / ROWS_B, TPB, 0, stream>>>();
    loss_kernel<<<1, 1024, 0, stream>>>(out);
}